// Round 1
// baseline (518.698 us; speedup 1.0000x reference)
//
#include <hip/hip_runtime.h>

typedef unsigned short u16;
typedef __attribute__((ext_vector_type(8))) __bf16 bf16x8;
typedef __attribute__((ext_vector_type(4))) float f32x4;

#define BB 4
#define SS 1024
#define DD 2048
#define HH 32
#define KVHN 8
#define HDIM 64

__device__ __forceinline__ u16 f2b(float f) {
    union { float f; unsigned u; } v; v.f = f;
    unsigned r = v.u + 0x7FFFu + ((v.u >> 16) & 1u);
    return (u16)(r >> 16);
}
__device__ __forceinline__ float b2f(u16 h) {
    union { unsigned u; float f; } v; v.u = ((unsigned)h) << 16; return v.f;
}

__device__ __forceinline__ f32x4 mfma16(bf16x8 a, bf16x8 b, f32x4 c) {
    return __builtin_amdgcn_mfma_f32_16x16x32_bf16(a, b, c, 0, 0, 0);
}

__device__ __forceinline__ void async_cp16(const void* g, void* l) {
    __builtin_amdgcn_global_load_lds((__attribute__((address_space(1))) void*)g,
                                     (__attribute__((address_space(3))) void*)l,
                                     16, 0, 0);
}

// ---------------- cast x (fp32 -> bf16) ----------------
__global__ __launch_bounds__(256) void cast_x_kernel(const float* __restrict__ x,
                                                     u16* __restrict__ xb) {
    int i = (blockIdx.x * 256 + threadIdx.x) * 4;
    float4 v = *(const float4*)(x + i);
    unsigned r0 = (unsigned)f2b(v.x) | ((unsigned)f2b(v.y) << 16);
    unsigned r1 = (unsigned)f2b(v.z) | ((unsigned)f2b(v.w) << 16);
    *(uint2*)(xb + i) = make_uint2(r0, r1);
}

// ---------------- weight transpose+cast: W[K=2048][N] fp32 -> Wt[(n+off)][2048] bf16 ----------------
__global__ __launch_bounds__(256) void wtrans_kernel(const float* __restrict__ W,
                                                     u16* __restrict__ Wt,
                                                     int N, int n_off) {
    __shared__ float tile[32][33];
    int n0 = blockIdx.x * 32;
    int k0 = blockIdx.y * 32;
    int tid = threadIdx.x;
    int nj = tid & 31;
    int ki = tid >> 5;  // 0..7
#pragma unroll
    for (int it = 0; it < 4; it++) {
        int kk = it * 8 + ki;
        tile[kk][nj] = W[(size_t)(k0 + kk) * N + n0 + nj];
    }
    __syncthreads();
#pragma unroll
    for (int it = 0; it < 4; it++) {
        int nn = it * 8 + ki;
        Wt[(size_t)(n0 + nn + n_off) * 2048 + k0 + nj] = f2b(tile[nj][nn]);
    }
}

// ---------------- GEMM: C[M][N] = A[M][K] * Bt[N][K]^T, bf16 in, bf16/f32 out ----------------
// 128x128 tile, BK=32, 256 threads (4 waves), 4x4 16x16x32 MFMA per wave.
template <int OUT_BF16>
__global__ __launch_bounds__(256) void gemm_bt(const u16* __restrict__ A,
                                               const u16* __restrict__ Bt,
                                               void* __restrict__ Cv,
                                               int M, int N, int K) {
    __shared__ __align__(16) u16 As[128 * 32];
    __shared__ __align__(16) u16 Bs[128 * 32];
    const int tid = threadIdx.x;
    const int lane = tid & 63;
    const int w = tid >> 6;
    const int m0 = blockIdx.y * 128;
    const int n0 = blockIdx.x * 128;
    const int wm = (w >> 1) * 64;
    const int wn = (w & 1) * 64;
    const int lr = lane & 15;
    const int lk = (lane >> 4) * 8;
    const int lq = (lane >> 4) * 4;

    const f32x4 zero4 = {0.f, 0.f, 0.f, 0.f};
    f32x4 acc[4][4];
#pragma unroll
    for (int i = 0; i < 4; i++)
#pragma unroll
        for (int j = 0; j < 4; j++) acc[i][j] = zero4;

    const int fb0 = tid * 16;          // byte offset in tile, shot 0
    const int row0 = fb0 >> 6;         // 0..63 (64B per 32-col bf16 row)
    const int col0 = (fb0 & 63) >> 1;  // 0,8,16,24

    for (int k0 = 0; k0 < K; k0 += 32) {
        async_cp16(A + (size_t)(m0 + row0) * K + k0 + col0, As + w * 512);
        async_cp16(A + (size_t)(m0 + row0 + 64) * K + k0 + col0, As + 2048 + w * 512);
        async_cp16(Bt + (size_t)(n0 + row0) * K + k0 + col0, Bs + w * 512);
        async_cp16(Bt + (size_t)(n0 + row0 + 64) * K + k0 + col0, Bs + 2048 + w * 512);
        __syncthreads();
        bf16x8 af[4], bfr[4];
#pragma unroll
        for (int mi = 0; mi < 4; mi++)
            af[mi] = *(const bf16x8*)(As + (wm + mi * 16 + lr) * 32 + lk);
#pragma unroll
        for (int ni = 0; ni < 4; ni++)
            bfr[ni] = *(const bf16x8*)(Bs + (wn + ni * 16 + lr) * 32 + lk);
#pragma unroll
        for (int mi = 0; mi < 4; mi++)
#pragma unroll
            for (int ni = 0; ni < 4; ni++)
                acc[mi][ni] = mfma16(af[mi], bfr[ni], acc[mi][ni]);
        __syncthreads();
    }

    if (OUT_BF16) {
        u16* C = (u16*)Cv;
#pragma unroll
        for (int mi = 0; mi < 4; mi++)
#pragma unroll
            for (int ni = 0; ni < 4; ni++)
#pragma unroll
                for (int i = 0; i < 4; i++) {
                    int r = m0 + wm + mi * 16 + lq + i;
                    int c = n0 + wn + ni * 16 + lr;
                    C[(size_t)r * N + c] = f2b(acc[mi][ni][i]);
                }
    } else {
        float* C = (float*)Cv;
#pragma unroll
        for (int mi = 0; mi < 4; mi++)
#pragma unroll
            for (int ni = 0; ni < 4; ni++)
#pragma unroll
                for (int i = 0; i < 4; i++) {
                    int r = m0 + wm + mi * 16 + lq + i;
                    int c = n0 + wn + ni * 16 + lr;
                    C[(size_t)r * N + c] = acc[mi][ni][i];
                }
    }
}

// ---------------- RoPE + reshape to head-major ----------------
// QKV[4096][3072] bf16 -> Qh[B][H][S][64], Kh[B][KVH][S][64]
__global__ __launch_bounds__(256) void rope_kernel(const u16* __restrict__ QKV,
                                                   const float* __restrict__ cosT,
                                                   const float* __restrict__ sinT,
                                                   u16* __restrict__ Qh,
                                                   u16* __restrict__ Kh) {
    int idx = blockIdx.x * 256 + threadIdx.x;  // (row*40 + hh)*32 + d
    int d = idx & 31;
    int t = idx >> 5;
    int hh = t % 40;
    int row = t / 40;      // b*S + s
    int s = row & (SS - 1);
    int b = row >> 10;
    float c = cosT[s * HDIM + d];
    float sn = sinT[s * HDIM + d];
    if (hh < 32) {
        const u16* src = QKV + (size_t)row * 3072 + hh * 64 + d;
        float x1 = b2f(src[0]), x2 = b2f(src[32]);
        u16* dst = Qh + ((size_t)(b * HH + hh) * SS + s) * 64 + d;
        dst[0] = f2b(x1 * c - x2 * sn);
        dst[32] = f2b(x2 * c + x1 * sn);
    } else {
        int g = hh - 32;
        const u16* src = QKV + (size_t)row * 3072 + 2048 + g * 64 + d;
        float x1 = b2f(src[0]), x2 = b2f(src[32]);
        u16* dst = Kh + ((size_t)(b * KVHN + g) * SS + s) * 64 + d;
        dst[0] = f2b(x1 * c - x2 * sn);
        dst[32] = f2b(x2 * c + x1 * sn);
    }
}

// ---------------- V transpose: QKV[.,2560+g*64+hd] -> Vt[B][KVH][64][S] ----------------
__global__ __launch_bounds__(256) void vtrans_kernel(const u16* __restrict__ QKV,
                                                     u16* __restrict__ Vt) {
    __shared__ u16 tile[64][65];
    int blk = blockIdx.x;  // b*KVH*16 + g*16 + st
    int st = blk & 15;
    int t2 = blk >> 4;
    int g = t2 & 7;
    int b = t2 >> 3;
    int tid = threadIdx.x;
    int cj = tid & 63;
    int ri = tid >> 6;  // 0..3
    const u16* src = QKV + ((size_t)(b * SS + st * 64)) * 3072 + 2560 + g * 64;
#pragma unroll
    for (int it = 0; it < 16; it++) {
        int s_i = it * 4 + ri;
        tile[s_i][cj] = src[(size_t)s_i * 3072 + cj];
    }
    __syncthreads();
    u16* dst = Vt + ((size_t)(b * KVHN + g) * HDIM) * SS + st * 64;
#pragma unroll
    for (int it = 0; it < 16; it++) {
        int hd_i = it * 4 + ri;
        dst[(size_t)hd_i * SS + cj] = tile[cj][hd_i];
    }
}

// ---------------- Flash attention ----------------
// grid (S/64, H, B), 256 threads. Wave w owns Q-rows [qt*64+w*16, +16).
__global__ __launch_bounds__(256) void flash_kernel(const u16* __restrict__ Qh,
                                                    const u16* __restrict__ Kh,
                                                    const u16* __restrict__ Vt,
                                                    u16* __restrict__ Attn) {
    __shared__ __align__(16) u16 Plds[4 * 16 * 64];
    const int tid = threadIdx.x;
    const int lane = tid & 63;
    const int w = tid >> 6;
    const int qt = blockIdx.x;
    const int h = blockIdx.y;
    const int b = blockIdx.z;
    const int g = h >> 2;  // N_REP = 4
    const int lr = lane & 15;
    const int lk8 = (lane >> 4) * 8;
    const int lq = (lane >> 4) * 4;
    const float cLog = 0.125f * 1.44269504088896f;  // scale * log2(e)

    const u16* Qbase = Qh + ((size_t)(b * HH + h) * SS + qt * 64 + w * 16) * HDIM;
    bf16x8 qa0 = *(const bf16x8*)(Qbase + (size_t)lr * HDIM + lk8);
    bf16x8 qa1 = *(const bf16x8*)(Qbase + (size_t)lr * HDIM + 32 + lk8);

    const u16* Kbase = Kh + (size_t)(b * KVHN + g) * SS * HDIM;
    const u16* Vbase = Vt + (size_t)(b * KVHN + g) * HDIM * SS;

    const f32x4 zero4 = {0.f, 0.f, 0.f, 0.f};
    float mrow[4], lrow[4];
    f32x4 o[4];
#pragma unroll
    for (int i = 0; i < 4; i++) { mrow[i] = -1e30f; lrow[i] = 0.f; o[i] = zero4; }

    u16* Pw = Plds + w * 16 * 64;

    for (int kt = 0; kt < SS; kt += 64) {
        f32x4 s[4];
#pragma unroll
        for (int nt = 0; nt < 4; nt++) {
            const u16* kp = Kbase + (size_t)(kt + nt * 16 + lr) * HDIM;
            bf16x8 kb0 = *(const bf16x8*)(kp + lk8);
            bf16x8 kb1 = *(const bf16x8*)(kp + 32 + lk8);
            f32x4 a = zero4;
            a = mfma16(qa0, kb0, a);
            a = mfma16(qa1, kb1, a);
            s[nt] = a;
        }
        float alpha[4], mnewv[4];
#pragma unroll
        for (int r = 0; r < 4; r++) {
            float mx = fmaxf(fmaxf(s[0][r], s[1][r]), fmaxf(s[2][r], s[3][r]));
            mx = fmaxf(mx, __shfl_xor(mx, 1));
            mx = fmaxf(mx, __shfl_xor(mx, 2));
            mx = fmaxf(mx, __shfl_xor(mx, 4));
            mx = fmaxf(mx, __shfl_xor(mx, 8));
            float mnew = fmaxf(mrow[r], mx);
            alpha[r] = __builtin_amdgcn_exp2f(cLog * (mrow[r] - mnew));
            mrow[r] = mnew;
            mnewv[r] = mnew;
        }
        float p[4][4];
#pragma unroll
        for (int nt = 0; nt < 4; nt++)
#pragma unroll
            for (int r = 0; r < 4; r++)
                p[nt][r] = __builtin_amdgcn_exp2f(cLog * (s[nt][r] - mnewv[r]));
#pragma unroll
        for (int r = 0; r < 4; r++) {
            float su = p[0][r] + p[1][r] + p[2][r] + p[3][r];
            su += __shfl_xor(su, 1);
            su += __shfl_xor(su, 2);
            su += __shfl_xor(su, 4);
            su += __shfl_xor(su, 8);
            lrow[r] = lrow[r] * alpha[r] + su;
        }
#pragma unroll
        for (int nt = 0; nt < 4; nt++)
#pragma unroll
            for (int r = 0; r < 4; r++) o[nt][r] *= alpha[r];
#pragma unroll
        for (int nt = 0; nt < 4; nt++)
#pragma unroll
            for (int r = 0; r < 4; r++)
                Pw[(lq + r) * 64 + nt * 16 + lr] = f2b(p[nt][r]);
        __syncthreads();
        bf16x8 pa0 = *(const bf16x8*)(Pw + lr * 64 + lk8);
        bf16x8 pa1 = *(const bf16x8*)(Pw + lr * 64 + 32 + lk8);
#pragma unroll
        for (int nt = 0; nt < 4; nt++) {
            const u16* vp = Vbase + (size_t)(nt * 16 + lr) * SS + kt;
            bf16x8 vb0 = *(const bf16x8*)(vp + lk8);
            bf16x8 vb1 = *(const bf16x8*)(vp + 32 + lk8);
            o[nt] = mfma16(pa0, vb0, o[nt]);
            o[nt] = mfma16(pa1, vb1, o[nt]);
        }
        __syncthreads();
    }

    u16* Ob = Attn + ((size_t)(b * SS + qt * 64 + w * 16)) * 2048 + h * 64;
#pragma unroll
    for (int nt = 0; nt < 4; nt++)
#pragma unroll
        for (int r = 0; r < 4; r++) {
            float val = o[nt][r] / lrow[r];
            Ob[(size_t)(lq + r) * 2048 + nt * 16 + lr] = f2b(val);
        }
}

// ---------------- launch ----------------
extern "C" void kernel_launch(void* const* d_in, const int* in_sizes, int n_in,
                              void* d_out, int out_size, void* d_ws, size_t ws_size,
                              hipStream_t stream) {
    (void)in_sizes; (void)n_in; (void)out_size; (void)ws_size;
    const float* x = (const float*)d_in[0];
    const float* cosT = (const float*)d_in[1];
    const float* sinT = (const float*)d_in[2];
    const float* Wq = (const float*)d_in[3];
    const float* Wk = (const float*)d_in[4];
    const float* Wv = (const float*)d_in[5];
    const float* Wo = (const float*)d_in[6];
    float* out = (float*)d_out;

    char* ws = (char*)d_ws;
    u16* Xb    = (u16*)(ws);                    // 4096*2048*2      = 16 MB
    u16* Wqkvt = (u16*)(ws + 16777216);         // 3072*2048*2      = 12 MB
    u16* Wot   = (u16*)(ws + 29360128);         // 2048*2048*2      = 8 MB
    u16* QKV   = (u16*)(ws + 37748736);         // 4096*3072*2      = 24 MB
    u16* Qh    = (u16*)(ws + 62914560);         // 4*32*1024*64*2   = 16 MB
    u16* Kh    = (u16*)(ws + 79691776);         // 4*8*1024*64*2    = 4 MB
    u16* Vt    = (u16*)(ws + 83886080);         // 4 MB
    u16* Attn  = (u16*)(ws + 88080384);         // 4096*2048*2      = 16 MB
    // total 104857600 bytes

    cast_x_kernel<<<8192, 256, 0, stream>>>(x, Xb);
    wtrans_kernel<<<dim3(64, 64), 256, 0, stream>>>(Wq, Wqkvt, 2048, 0);
    wtrans_kernel<<<dim3(16, 64), 256, 0, stream>>>(Wk, Wqkvt, 512, 2048);
    wtrans_kernel<<<dim3(16, 64), 256, 0, stream>>>(Wv, Wqkvt, 512, 2560);
    wtrans_kernel<<<dim3(64, 64), 256, 0, stream>>>(Wo, Wot, 2048, 0);

    gemm_bt<1><<<dim3(24, 32), 256, 0, stream>>>(Xb, Wqkvt, (void*)QKV, 4096, 3072, 2048);

    rope_kernel<<<20480, 256, 0, stream>>>(QKV, cosT, sinT, Qh, Kh);
    vtrans_kernel<<<512, 256, 0, stream>>>(QKV, Vt);

    flash_kernel<<<dim3(16, 32, 4), 256, 0, stream>>>(Qh, Kh, Vt, Attn);

    gemm_bt<0><<<dim3(16, 32), 256, 0, stream>>>(Attn, Wot, (void*)out, 4096, 2048, 2048);
}